// Round 13
// baseline (295.120 us; speedup 1.0000x reference)
//
#include <hip/hip_runtime.h>
#include <hip/hip_cooperative_groups.h>
#include <cfloat>

namespace cg = cooperative_groups;

// Problem constants
#define BS 16
#define CC 512
#define HWD 1024      // h*w
#define NN 16384      // BS*HWD rows
#define MM 8          // sub-codebooks
#define NE 1024       // codes per sub-codebook
#define ED 64         // code dim

// d_out layout (all read back as float32):
#define LOSS_OFF 8388608
#define IDX_OFF  8388609
#define BIN_OFF  8519681

// flag margin: ref fp32 quantization perturbs d by <=~1.5e-5; phase-1 err ~3e-6
#define TAU 4e-5f
// candidate window in raw float-bit units (>= 2.38e-5 in value space)
#define UWIN 400u

// workspace byte offsets
#define WS_B     0            // float[MM*NE] emulated np ||e||^2        (32 KB)
#define WS_BMAT  3866656      // uint4[8*9*32*64] bf16 frag-order B      (2.25 MB)

#define PREP_TOTAL (MM * NE + MM * 9 * 2048)   // 8192 + 147456

typedef __attribute__((ext_vector_type(8))) short bf16x8;
typedef __attribute__((ext_vector_type(16))) float f32x16;

// ---- bf16 helpers ---------------------------------------------------------
__device__ __forceinline__ unsigned short f2bf(float f) {
    unsigned int u = __float_as_uint(f);
    unsigned int r = (u + 0x7fffu + ((u >> 16) & 1u)) >> 16;
    return (unsigned short)r;
}
__device__ __forceinline__ float bf2f(unsigned short h) {
    return __uint_as_float(((unsigned int)h) << 16);
}
__device__ __forceinline__ unsigned umin_(unsigned a, unsigned b) { return a < b ? a : b; }
__device__ __forceinline__ unsigned umax_(unsigned a, unsigned b) { return a > b ? a : b; }
__device__ __forceinline__ unsigned umin3(unsigned a, unsigned b, unsigned c) {
    return umin_(umin_(a, b), c);
}

// ---- fp32 ops with contraction disabled -----------------------------------
__device__ __forceinline__ float mul_rn(float a, float b) {
#pragma clang fp contract(off)
    return a * b;
}
__device__ __forceinline__ float add_rn(float a, float b) {
#pragma clang fp contract(off)
    return a + b;
}
__device__ __forceinline__ float sub_rn(float a, float b) {
#pragma clang fp contract(off)
    return a - b;
}

// numpy FLOAT_pairwise_sum over fl(x_d^2), n=64
__device__ __forceinline__ float np_sumsq64(const float* x) {
    float r[8];
#pragma unroll
    for (int j = 0; j < 8; ++j) r[j] = mul_rn(x[j], x[j]);
#pragma unroll
    for (int i = 8; i < 64; i += 8) {
#pragma unroll
        for (int j = 0; j < 8; ++j) r[j] = add_rn(r[j], mul_rn(x[i + j], x[i + j]));
    }
    return add_rn(add_rn(add_rn(r[0], r[1]), add_rn(r[2], r[3])),
                  add_rn(add_rn(r[4], r[5]), add_rn(r[6], r[7])));
}

// numpy einsum sum_of_products_contig_two, SSE npyv (no FMA); z from LDS ptr
__device__ __forceinline__ float np_dot64(const float* zsh, const float4* cr4) {
    float v0 = 0.f, v1 = 0.f, v2 = 0.f, v3 = 0.f;
#pragma unroll
    for (int t = 0; t < 4; ++t) {
        float4 e0 = cr4[t * 4 + 0];
        float4 e1 = cr4[t * 4 + 1];
        float4 e2 = cr4[t * 4 + 2];
        float4 e3 = cr4[t * 4 + 3];
        const int d0 = 16 * t;
        v0 = add_rn(mul_rn(zsh[d0 + 0], e0.x),
             add_rn(mul_rn(zsh[d0 + 4], e1.x),
             add_rn(mul_rn(zsh[d0 + 8], e2.x),
             add_rn(mul_rn(zsh[d0 + 12], e3.x), v0))));
        v1 = add_rn(mul_rn(zsh[d0 + 1], e0.y),
             add_rn(mul_rn(zsh[d0 + 5], e1.y),
             add_rn(mul_rn(zsh[d0 + 9], e2.y),
             add_rn(mul_rn(zsh[d0 + 13], e3.y), v1))));
        v2 = add_rn(mul_rn(zsh[d0 + 2], e0.z),
             add_rn(mul_rn(zsh[d0 + 6], e1.z),
             add_rn(mul_rn(zsh[d0 + 10], e2.z),
             add_rn(mul_rn(zsh[d0 + 14], e3.z), v2))));
        v3 = add_rn(mul_rn(zsh[d0 + 3], e0.w),
             add_rn(mul_rn(zsh[d0 + 7], e1.w),
             add_rn(mul_rn(zsh[d0 + 11], e2.w),
             add_rn(mul_rn(zsh[d0 + 15], e3.w), v3))));
    }
    return add_rn(add_rn(v0, v1), add_rn(v2, v3));
}

// ---------------------------------------------------------------------------
// Single fused cooperative kernel:
//   Phase P (prep: Bhat + Bmat + zero-init)  -> grid.sync ->
//   per-tile loop: Phase 1 (R9 argmin, LDS handoff of pack/cands) ->
//                  Phase 2 (fixup + outputs), both block-local.
// Removes 2 launch boundaries (~40 us of the 96 us non-argmin time) and the
// idxw/cand global round-trips. All verified numerics unchanged.
__global__ __launch_bounds__(512, 4) void fused_kernel(
        const float* __restrict__ z, const float* __restrict__ cb,
        float* __restrict__ Bhat, uint4* __restrict__ Bmat,
        float* __restrict__ out) {
    const int tid = threadIdx.x;
    const int bid = blockIdx.x;
    const int nblk = gridDim.x;

    union SMem {
        uint4 ldsB[3][9 * 2 * 64];              // 54 KB argmin staging
        struct {
            int hist[NE];                        // 4 KB
            int ridx[256];
            int pks[256];
            short flist[256];
            int fcnt;
            float zsh[8][ED];                    // 2 KB
            double wsum[8];
            unsigned short candl[256][12];       // 6 KB
        } o;
    };
    __shared__ SMem sm;

    // ---------------- Phase P: prep ----------------
    for (int gt = bid * 512 + tid; gt < PREP_TOTAL; gt += nblk * 512) {
        if (gt < MM * NE) {
            if (gt == 0) out[LOSS_OFF] = 0.0f;
            if (gt < NE) out[BIN_OFF + gt] = 0.0f;
            const float4* r4 = (const float4*)(cb + (size_t)gt * ED);
            float x[ED];
#pragma unroll
            for (int q = 0; q < 16; ++q) {
                float4 v = r4[q];
                x[q*4+0] = v.x; x[q*4+1] = v.y; x[q*4+2] = v.z; x[q*4+3] = v.w;
            }
            Bhat[gt] = np_sumsq64(x);
        } else {
            int t = gt - MM * NE;                // [0, 8*9*2048)
            int lane = t & 63;
            int ct = (t >> 6) & 31;
            int rem = t >> 11;
            int c = rem % 9;
            int mm = rem / 9;
            int hh = lane >> 5;
            int k = ct * 32 + (lane & 31);

            unsigned short v[8];
#pragma unroll
            for (int j = 0; j < 8; ++j) v[j] = 0;
            if (c < 8) {
                int d0 = 16 * (c & 3) + 8 * hh;
                const float* e = cb + ((size_t)mm * NE + k) * ED + d0;
#pragma unroll
                for (int j = 0; j < 8; ++j) {
                    float f = -2.0f * e[j];
                    unsigned short hi = f2bf(f);
                    v[j] = (c >= 4) ? f2bf(f - bf2f(hi)) : hi;
                }
            } else if (hh == 0) {
                const float* e = cb + ((size_t)mm * NE + k) * ED;
                float s = 0.f;
#pragma unroll
                for (int d = 0; d < ED; ++d) s += e[d] * e[d];
                v[0] = f2bf(s);                  // ||e||^2 (bf16)
                v[1] = 0x3F80;                   // + 1.0 shift
            }
            uint4 o4;
            o4.x = (unsigned)v[0] | ((unsigned)v[1] << 16);
            o4.y = (unsigned)v[2] | ((unsigned)v[3] << 16);
            o4.z = (unsigned)v[4] | ((unsigned)v[5] << 16);
            o4.w = (unsigned)v[6] | ((unsigned)v[7] << 16);
            Bmat[t] = o4;
        }
    }
    __threadfence();
    cg::this_grid().sync();

    const int w = tid >> 6;
    const int l = tid & 63;
    const int h = l >> 5;
    const int r5 = l & 31;

    // ---------------- per-tile: argmin + output ----------------
    for (int u = bid; u < 512; u += nblk) {
        __syncthreads();                        // sm reuse across tiles
        const int m = u >> 6;
        const int row0 = (u & 63) * 256;

        const int n_mine = row0 + w * 32 + r5;
        const int b = n_mine >> 10;
        const int hw = n_mine & (HWD - 1);
        const float* zbase = z + (((size_t)(b * CC + m * ED)) << 10) + hw;

        bf16x8 zh[4], zl[4];
#pragma unroll
        for (int i = 0; i < 4; ++i) {
            int o = 2 * i + h;
#pragma unroll
            for (int j = 0; j < 8; ++j) {
                float f = zbase[(size_t)(8 * o + j) << 10];
                unsigned short hb = f2bf(f);
                unsigned short lb = f2bf(f - bf2f(hb));
                zh[i][j] = (short)hb;
                zl[i][j] = (short)lb;
            }
        }
        bf16x8 ones12 = {0, 0, 0, 0, 0, 0, 0, 0};
        if (h == 0) { ones12[0] = (short)0x3F80; ones12[1] = (short)0x3F80; }

        unsigned rbm = 0xFFFFFFF0u, rsec = 0xFFFFFFFFu, rinfo = 0;
        int ccnt = 0;
        unsigned cq0 = 0, cq1 = 0, cq2 = 0;
        auto push = [&](unsigned id) {
            cq2 = (cq2 << 16) | (cq1 >> 16);
            cq1 = (cq1 << 16) | (cq0 >> 16);
            cq0 = (cq0 << 16) | (id & 0xFFFFu);
            ccnt++;
        };

        auto stage = [&](int g, int bufi) {
            for (int seg = w; seg < 18; seg += 8) {
                int c = seg >> 1, ct2 = seg & 1;
                const uint4* src = Bmat +
                    ((size_t)((m * 9 + c) * 32 + (g * 2 + ct2)) << 6) + l;
                uint4* dst = &sm.ldsB[bufi][(c * 2 + ct2) * 64];
                __builtin_amdgcn_global_load_lds(
                    (const __attribute__((address_space(1))) unsigned int*)src,
                    (__attribute__((address_space(3))) unsigned int*)dst, 16, 0, 0);
            }
        };

        auto process = [&](const f32x16& acc, unsigned tile) {
            unsigned uu[16];
#pragma unroll
            for (int s = 0; s < 16; ++s)
                uu[s] = (__float_as_uint(acc[s]) & 0xFFFFFFF0u) | (unsigned)s;
            unsigned b0 = umin_(uu[0], uu[1]),  s0 = umax_(uu[0], uu[1]);
            unsigned b1 = umin_(uu[2], uu[3]),  s1 = umax_(uu[2], uu[3]);
            unsigned b2 = umin_(uu[4], uu[5]),  s2 = umax_(uu[4], uu[5]);
            unsigned b3 = umin_(uu[6], uu[7]),  s3 = umax_(uu[6], uu[7]);
            unsigned b4 = umin_(uu[8], uu[9]),  s4 = umax_(uu[8], uu[9]);
            unsigned b5 = umin_(uu[10], uu[11]), s5 = umax_(uu[10], uu[11]);
            unsigned b6 = umin_(uu[12], uu[13]), s6 = umax_(uu[12], uu[13]);
            unsigned b7 = umin_(uu[14], uu[15]), s7 = umax_(uu[14], uu[15]);
            unsigned B0 = umin_(b0, b1), S0 = umin3(umax_(b0, b1), s0, s1);
            unsigned B1 = umin_(b2, b3), S1 = umin3(umax_(b2, b3), s2, s3);
            unsigned B2 = umin_(b4, b5), S2 = umin3(umax_(b4, b5), s4, s5);
            unsigned B3 = umin_(b6, b7), S3 = umin3(umax_(b6, b7), s6, s7);
            unsigned C0 = umin_(B0, B1), T0 = umin3(umax_(B0, B1), S0, S1);
            unsigned C1 = umin_(B2, B3), T1 = umin3(umax_(B2, B3), S2, S3);
            unsigned bt = umin_(C0, C1), st = umin3(umax_(C0, C1), T0, T1);

            unsigned oldrbm = rbm;
            bool take = bt < oldrbm;
            unsigned newrbm = take ? bt : oldrbm;
            unsigned limit = newrbm + UWIN;
            rsec = umin3(rsec, st, take ? oldrbm : bt);
            int sbt = (int)(bt & 15u);
            if (take) {
                if (bt + UWIN < oldrbm) ccnt = 0;
                push(tile * 32u + ((unsigned)sbt & 3u) +
                     8u * ((unsigned)sbt >> 2) + 4u * (unsigned)h);
                rinfo = (tile << 4) | (unsigned)sbt;
            }
            rbm = newrbm;
            unsigned gatev = take ? st : bt;
            if (gatev < limit) {
#pragma unroll
                for (int s = 0; s < 16; ++s) {
                    if (uu[s] < limit && !(take && s == sbt))
                        push(tile * 32u + ((unsigned)s & 3u) +
                             8u * ((unsigned)s >> 2) + 4u * (unsigned)h);
                }
            }
        };

        // prologue: prefetch depth 2
        stage(0, 0);
        stage(1, 1);
        asm volatile("s_waitcnt vmcnt(2)" ::: "memory");
        __builtin_amdgcn_s_barrier();

        int bR = 0;
        for (int g = 0; g < 16; ++g) {
            int bW = bR + 2; if (bW >= 3) bW -= 3;
            if (g < 14) stage(g + 2, bW);
            const uint4* Bb = &sm.ldsB[bR][0];

            f32x16 a0, a1;
#pragma unroll
            for (int s = 0; s < 16; ++s) { a0[s] = 0.0f; a1[s] = 0.0f; }
            bf16x8 sh0[4], sh1[4];
            __builtin_amdgcn_s_setprio(1);
#pragma unroll
            for (int c = 0; c < 4; ++c) {          // cc = 0..3 (hi x zh)
                bf16x8 af0 = *(const bf16x8*)&Bb[(c * 2 + 0) * 64 + l];
                bf16x8 af1 = *(const bf16x8*)&Bb[(c * 2 + 1) * 64 + l];
                sh0[c] = af0; sh1[c] = af1;
                a0 = __builtin_amdgcn_mfma_f32_32x32x16_bf16(af0, zh[c], a0, 0, 0, 0);
                a1 = __builtin_amdgcn_mfma_f32_32x32x16_bf16(af1, zh[c], a1, 0, 0, 0);
            }
#pragma unroll
            for (int c = 4; c < 8; ++c) {          // cc = 4..7 (lo x zh)
                bf16x8 af0 = *(const bf16x8*)&Bb[(c * 2 + 0) * 64 + l];
                bf16x8 af1 = *(const bf16x8*)&Bb[(c * 2 + 1) * 64 + l];
                a0 = __builtin_amdgcn_mfma_f32_32x32x16_bf16(af0, zh[c & 3], a0, 0, 0, 0);
                a1 = __builtin_amdgcn_mfma_f32_32x32x16_bf16(af1, zh[c & 3], a1, 0, 0, 0);
            }
#pragma unroll
            for (int c = 0; c < 4; ++c) {          // cc = 8..11 (hi x zl)
                a0 = __builtin_amdgcn_mfma_f32_32x32x16_bf16(sh0[c], zl[c], a0, 0, 0, 0);
                a1 = __builtin_amdgcn_mfma_f32_32x32x16_bf16(sh1[c], zl[c], a1, 0, 0, 0);
            }
            {                                       // cc = 12 (norm + shift)
                bf16x8 af0 = *(const bf16x8*)&Bb[(8 * 2 + 0) * 64 + l];
                bf16x8 af1 = *(const bf16x8*)&Bb[(8 * 2 + 1) * 64 + l];
                a0 = __builtin_amdgcn_mfma_f32_32x32x16_bf16(af0, ones12, a0, 0, 0, 0);
                a1 = __builtin_amdgcn_mfma_f32_32x32x16_bf16(af1, ones12, a1, 0, 0, 0);
            }
            __builtin_amdgcn_s_setprio(0);
            process(a0, (unsigned)(g * 2 + 0));
            process(a1, (unsigned)(g * 2 + 1));

            if (g < 14) {
                asm volatile("s_waitcnt vmcnt(2)" ::: "memory");
            } else if (g == 14) {
                asm volatile("s_waitcnt vmcnt(0)" ::: "memory");
            }
            if (g < 15) __builtin_amdgcn_s_barrier();
            bR = (bR == 2) ? 0 : bR + 1;
        }

        __syncthreads();        // ldsB dead; union now used as sm.o

        // zero hist, init fcnt, flush candidate queue + pack to LDS
        sm.o.hist[tid] = 0;
        sm.o.hist[tid + 512] = 0;
        if (tid == 0) sm.o.fcnt = 0;
        const int lrow = w * 32 + r5;
        if (ccnt) {
            unsigned* cp = (unsigned*)&sm.o.candl[lrow][h * 6];
            cp[0] = cq0; cp[1] = cq1; cp[2] = cq2;
        }
        int pcnt = __shfl_xor(ccnt, 32, 64);
        {
            unsigned ss = rinfo & 15u, tile = rinfo >> 4;
            int k = (int)(tile * 32 + (ss & 3u) + 8u * (ss >> 2) + 4u * (unsigned)h);
            unsigned orbm = __shfl_xor(rbm, 32, 64);
            int ok = __shfl_xor(k, 32, 64);
            unsigned orsec = __shfl_xor(rsec, 32, 64);
            bool take = orbm < rbm;
            unsigned lose = take ? rbm : orbm;
            unsigned fb = take ? orbm : rbm;
            int fk = take ? ok : k;
            unsigned fs = umin3(rsec, orsec, lose);
            if (l < 32) {
                int pack = fk;
                float margin = __uint_as_float(fs & 0xFFFFFFF0u) -
                               __uint_as_float(fb & 0xFFFFFFF0u);
                if (margin < TAU) {
                    int c0 = ccnt > 6 ? 7 : ccnt;   // 7 = overflow sentinel
                    int c1 = pcnt > 6 ? 7 : pcnt;
                    pack |= (1 << 30) | (c0 << 16) | (c1 << 20);
                }
                sm.o.pks[lrow] = pack;
            }
        }
        __syncthreads();

        // Phase A: decode, collect flagged rows
        if (tid < 256) {
            int pk = sm.o.pks[tid];
            sm.o.ridx[tid] = pk & 1023;
            if (pk & (1 << 30)) {
                int q = atomicAdd(&sm.o.fcnt, 1);
                sm.o.flist[q] = (short)tid;
            }
        }
        __syncthreads();

        // Phase B: wave-per-row exact fixup (identical math to cand/emul)
        const int fc = sm.o.fcnt;
        for (int r = w; r < fc; r += 8) {
            const int t = sm.o.flist[r];
            const int rn = row0 + t;
            const int rb = rn >> 10;
            const int rhw = rn & (HWD - 1);
            const int c0 = (sm.o.pks[t] >> 16) & 15;
            const int c1 = (sm.o.pks[t] >> 20) & 15;

            sm.o.zsh[w][l] = z[(((size_t)(rb * CC + m * ED + l)) << 10) + rhw];
            float A = np_sumsq64(&sm.o.zsh[w][0]);

            int kk;
            if (c0 == 7 || c1 == 7) {
                const float* cbm = cb + (size_t)m * NE * ED;
                const float* Bm = Bhat + m * NE;
                float best = FLT_MAX;
                int bidx = NE;
                for (int i = 0; i < 16; ++i) {
                    const int k = i * 64 + l;
                    const float4* cr4 = (const float4*)(cbm + (size_t)k * ED);
                    float C = np_dot64(&sm.o.zsh[w][0], cr4);
                    float dk = sub_rn(add_rn(A, Bm[k]), mul_rn(2.0f, C));
                    if (dk < best || (dk == best && k < bidx)) { best = dk; bidx = k; }
                }
#pragma unroll
                for (int off = 32; off >= 1; off >>= 1) {
                    float ov = __shfl_down(best, off, 64);
                    int oi = __shfl_down(bidx, off, 64);
                    if (ov < best || (ov == best && oi < bidx)) { best = ov; bidx = oi; }
                }
                kk = bidx;
            } else {
                int kj = -1;
                if (l < c0) kj = sm.o.candl[t][l];
                else if (l >= 8 && l < 8 + c1) kj = sm.o.candl[t][6 + (l - 8)];

                float dref = FLT_MAX;
                if (kj >= 0) {
                    const float4* cr4 = (const float4*)(cb + ((size_t)m * NE + kj) * ED);
                    float C = np_dot64(&sm.o.zsh[w][0], cr4);
                    dref = sub_rn(add_rn(A, Bhat[m * NE + kj]), mul_rn(2.0f, C));
                }
                int ki = (kj >= 0) ? kj : NE;
#pragma unroll
                for (int off = 32; off >= 1; off >>= 1) {
                    float ov = __shfl_down(dref, off, 64);
                    int oi = __shfl_down(ki, off, 64);
                    if (ov < dref || (ov == dref && oi < ki)) { dref = ov; ki = oi; }
                }
                kk = ki;
            }
            if (l == 0) sm.o.ridx[t] = kk;
        }
        __syncthreads();

        // idx + per-block histogram
        if (tid < 256) {
            int ir = sm.o.ridx[tid];
            out[IDX_OFF + m * NN + row0 + tid] = (float)ir;
            atomicAdd(&sm.o.hist[ir], 1);
        }

        // Phase C: vectorized copy. lane q -> rows 4q..4q+3, wave w -> d range
        const int b2 = row0 >> 10;
        const int hw0 = row0 & (HWD - 1);
        const int q = l;
        const int i0 = sm.o.ridx[4 * q + 0];
        const int i1 = sm.o.ridx[4 * q + 1];
        const int i2 = sm.o.ridx[4 * q + 2];
        const int i3 = sm.o.ridx[4 * q + 3];
        const float* cr0 = cb + ((size_t)m * NE + i0) * ED;
        const float* cr1 = cb + ((size_t)m * NE + i1) * ED;
        const float* cr2 = cb + ((size_t)m * NE + i2) * ED;
        const float* cr3 = cb + ((size_t)m * NE + i3) * ED;

        double acc = 0.0;
#pragma unroll
        for (int dd = 0; dd < 8; ++dd) {
            const int d = 8 * w + dd;
            const size_t off = (((size_t)(b2 * CC + m * ED + d)) << 10) + hw0 + 4 * q;
            float4 zz = *(const float4*)(z + off);
            float4 vv;
            vv.x = cr0[d]; vv.y = cr1[d]; vv.z = cr2[d]; vv.w = cr3[d];
            *(float4*)(out + off) = vv;
            float dx = vv.x - zz.x, dy = vv.y - zz.y;
            float dz2 = vv.z - zz.z, dw = vv.w - zz.w;
            acc += (double)dx * dx + (double)dy * dy;
            acc += (double)dz2 * dz2 + (double)dw * dw;
        }
#pragma unroll
        for (int off = 32; off >= 1; off >>= 1)
            acc += __shfl_down(acc, off, 64);
        if (l == 0) sm.o.wsum[w] = acc;
        __syncthreads();
        if (tid == 0) {
            double t2 = 0.0;
#pragma unroll
            for (int i = 0; i < 8; ++i) t2 += sm.o.wsum[i];
            atomicAdd(out + LOSS_OFF, (float)(t2 * (1.25 / 1048576.0)));
        }
        __syncthreads();
        {
            int v0 = sm.o.hist[tid];
            if (v0) atomicAdd(out + BIN_OFF + tid, (float)v0);
            int v1 = sm.o.hist[tid + 512];
            if (v1) atomicAdd(out + BIN_OFF + tid + 512, (float)v1);
        }
    }
}

// ---------------------------------------------------------------------------
extern "C" void kernel_launch(void* const* d_in, const int* in_sizes, int n_in,
                              void* d_out, int out_size, void* d_ws, size_t ws_size,
                              hipStream_t stream) {
    const float* z = (const float*)d_in[0];    // (16,512,32,32) fp32
    const float* cb = (const float*)d_in[1];   // (8,1024,64) fp32
    float* out = (float*)d_out;
    char* ws = (char*)d_ws;
    float* Bhat = (float*)(ws + WS_B);
    uint4* Bmat = (uint4*)(ws + WS_BMAT);

    static int g_grid = 0;
    if (g_grid == 0) {
        int nb = 0;
        hipOccupancyMaxActiveBlocksPerMultiprocessor(&nb, fused_kernel, 512, 0);
        if (nb < 1) nb = 1;
        long cap = (long)nb * 256;             // 256 CUs on MI355X
        g_grid = cap < 512 ? (int)cap : 512;
    }

    void* args[] = { (void*)&z, (void*)&cb, (void*)&Bhat, (void*)&Bmat,
                     (void*)&out };
    hipLaunchCooperativeKernel((const void*)fused_kernel, dim3(g_grid),
                               dim3(512), args, 0, stream);
}